// Round 7
// baseline (418.080 us; speedup 1.0000x reference)
//
#include <hip/hip_runtime.h>
#include <hip/hip_bf16.h>

// B=4, S=4096, E=256, NC=16, fp32 in/out. ONE persistent kernel (grid 512,
// 2 blocks/CU guaranteed: launch_bounds(256,2) + 74KB LDS) + an 8-byte
// memset for the grid-barrier counters.
//   phase 1 qkv: 768 units grid-strided over 512 blocks (unit bid and
//     bid+512; 512%8==0 keeps the XCD-affinity decode intact). R6 body:
//     x fp32->reg->bf16, w issue-early/write-late into swizzled LDS dbuf,
//     one barrier per K-step. Also zeroes the fp32 partial accumulator.
//   grid barrier (device-scope atomics + __threadfence; all blocks resident)
//   phase 2 flash: BYTE-IDENTICAL R6 structure (u=2, K/V dbuf + padded ps,
//     one barrier/chunk, one-behind PV, hoisted af, setprio, XCD decode,
//     fused wo-projection epilogue + atomicAdd into partial).
//   grid barrier
//   phase 3 norm: out = partial * (1/16)/ltot + bo  (2 elems/thread).
// Rationale (R4/R6 evidence): residual (total - flash) is 89.0us invariant
// to qkv structure and launch count -> either inter-launch overhead (this
// kills it) or a hidden qkv cost (this makes it directly measurable).

#define S_ 4096
#define E_ 256
#define B_ 4
#define NC_ 16
#define BS_ (B_ * S_)
#define NS_ 4

typedef __attribute__((ext_vector_type(8))) short bf16x8;
typedef __attribute__((ext_vector_type(4))) float f32x4;

__device__ __forceinline__ unsigned short bf16_rtne(float f) {
    unsigned int u = __float_as_uint(f);
    return (unsigned short)((u + 0x7FFFu + ((u >> 16) & 1u)) >> 16);
}
__device__ __forceinline__ bf16x8 pack8(f32x4 a, f32x4 b) {
    bf16x8 r;
#pragma unroll
    for (int i = 0; i < 4; i++) r[i] = (short)bf16_rtne(a[i]);
#pragma unroll
    for (int i = 0; i < 4; i++) r[4 + i] = (short)bf16_rtne(b[i]);
    return r;
}
__device__ __forceinline__ void gl_lds16(const void* g, void* lds) {
    __builtin_amdgcn_global_load_lds(
        (const __attribute__((address_space(1))) unsigned int*)g,
        (__attribute__((address_space(3))) unsigned int*)lds, 16, 0, 0);
}
// XOR swizzle on 16B LDS units: involution (mask from bits >=3 flips bits 0-2).
__device__ __forceinline__ int swz_u(int q) { return q ^ ((q >> 3) & 7); }

// Grid barrier: all 512 blocks co-resident (2/CU by construction).
// Release: per-thread fence (drain own stores, wb L2) + block sync, then one
// arrival atomic. Acquire: block sync + per-thread fence (invalidate).
__device__ __forceinline__ void gbar(unsigned* ctr, unsigned nblk) {
    __threadfence();
    __syncthreads();
    if (threadIdx.x == 0) {
        atomicAdd(ctr, 1u);
        while (atomicAdd(ctr, 0u) < nblk) __builtin_amdgcn_s_sleep(2);
    }
    __syncthreads();
    __threadfence();
}

__global__ __launch_bounds__(256, 2) void fused(
    const float* __restrict__ x, const float* __restrict__ wq,
    const float* __restrict__ wk, const float* __restrict__ wv,
    const float* __restrict__ bq, const float* __restrict__ bk,
    const float* __restrict__ bv, const float* __restrict__ wo,
    const float* __restrict__ bo, short* __restrict__ Qb,
    short* __restrict__ Kb, short* __restrict__ Vtc,
    float* __restrict__ partial, float* __restrict__ lpart,
    unsigned* __restrict__ bars, float* __restrict__ out) {
    __shared__ __align__(16) short lds[37888]; // 75776 B
    int t = threadIdx.x;
    int bid = blockIdx.x; // 0..511
    int lane = t & 63, wid = t >> 6, quad = lane >> 4, idx = lane & 15;
    f32x4 zf = {0.f, 0.f, 0.f, 0.f};

    // ================= phase 1: qkv (R6 body; stg=lds[0..16383],
    // epi=lds[16384..33279]) + partial zeroing =================
    {
        int z = bid * 256 + t;
        partial[z] = 0.f;
        partial[z + 131072] = 0.f;
    }
    for (int pass = 0; pass < 2; ++pass) {
        if (pass == 1 && bid >= 256) break;
        int lin = bid + pass * 512;
        int xcd = lin & 7, r8 = lin >> 3;
        int sel = r8 >> 5;
        int m0 = (((xcd << 5) | (r8 & 31))) * 64;

        const float* wsel = (sel == 0) ? wq : (sel == 1) ? wk : wv;
        const float* bias = (sel == 0) ? bq : (sel == 1) ? bk : bv;
        short* ep = lds + 16384;

        const float* wsrc[4];
#pragma unroll
        for (int i = 0; i < 4; i++) {
            int q = i * 256 + t, u = swz_u(q);
            wsrc[i] = wsel + (size_t)(u >> 2) * E_ + (u & 3) * 8;
        }
        f32x4 wf[8];
#pragma unroll
        for (int i = 0; i < 4; i++) {
            wf[i * 2] = *(const f32x4*)(wsrc[i]);
            wf[i * 2 + 1] = *(const f32x4*)(wsrc[i] + 4);
        }
        const float* xrow = x + (size_t)(m0 + wid * 16 + idx) * E_ + quad * 8;
        bf16x8 af[8];
#pragma unroll
        for (int it = 0; it < 8; it++) {
            f32x4 a0 = *(const f32x4*)(xrow + it * 32);
            f32x4 a1 = *(const f32x4*)(xrow + it * 32 + 4);
            af[it] = pack8(a0, a1);
        }
#pragma unroll
        for (int i = 0; i < 4; i++)
            *(bf16x8*)&lds[(i * 256 + t) * 8] = pack8(wf[i * 2], wf[i * 2 + 1]);

        f32x4 acc[16];
#pragma unroll
        for (int i = 0; i < 16; i++) acc[i] = zf;
        int fo = (idx * 4 + quad) ^ (idx >> 1);

        __syncthreads(); // buf 0 visible
#pragma unroll
        for (int it = 0; it < 8; it++) {
            if (it < 7) {
                int kc = (it + 1) * 32;
#pragma unroll
                for (int i = 0; i < 4; i++) {
                    wf[i * 2] = *(const f32x4*)(wsrc[i] + kc);
                    wf[i * 2 + 1] = *(const f32x4*)(wsrc[i] + kc + 4);
                }
            }
            const short* cw = &lds[((it & 1) * 1024 + fo) * 8];
            __builtin_amdgcn_s_setprio(1);
#pragma unroll
            for (int ct = 0; ct < 16; ct++)
                acc[ct] = __builtin_amdgcn_mfma_f32_16x16x32_bf16(
                    af[it], *(const bf16x8*)&cw[ct * 512], acc[ct], 0, 0, 0);
            __builtin_amdgcn_s_setprio(0);
            if (it < 7) {
                short* d = lds + ((it + 1) & 1) * 8192;
#pragma unroll
                for (int i = 0; i < 4; i++)
                    *(bf16x8*)&d[(i * 256 + t) * 8] = pack8(wf[i * 2], wf[i * 2 + 1]);
            }
            __syncthreads();
        }

        int qr = quad * 4;
        if (sel == 2) {
#pragma unroll
            for (int ct = 0; ct < 16; ct++) {
                int e = ct * 16 + idx;
                float bb = bias[e];
#pragma unroll
                for (int r = 0; r < 4; r++) {
                    int mr = wid * 16 + qr + r;
                    int ckg = mr >> 5, sin = mr & 31;
                    int sp = ((sin & 15) << 1) | (sin >> 4);
                    int pos = (sp >> 3) ^ ((e >> 1) & 3);
                    ep[ckg * 8192 + e * 32 + pos * 8 + (sp & 7)] =
                        (short)bf16_rtne(acc[ct][r] + bb);
                }
            }
            __syncthreads();
            size_t base = ((size_t)((m0 >> 12) * 128 + ((m0 & (S_ - 1)) >> 5))) * 8192;
#pragma unroll
            for (int j = 0; j < 8; j++) {
                int unit = j * 256 + t;
                *(bf16x8*)(Vtc + base + (size_t)unit * 8) = *(const bf16x8*)&ep[unit * 8];
            }
        } else {
            float alpha = (sel == 0) ? 0.0625f : 1.0f;
#pragma unroll
            for (int ct = 0; ct < 16; ct++) {
                int n = ct * 16 + idx;
                float bb = bias[n];
#pragma unroll
                for (int r = 0; r < 4; r++) {
                    int row = wid * 16 + qr + r;
                    int col = (sel == 1) ? ((((n >> 3) ^ (row & 7)) << 3) | (n & 7)) : n;
                    ep[row * 264 + col] = (short)bf16_rtne((acc[ct][r] + bb) * alpha);
                }
            }
            __syncthreads();
            short* o = (sel == 0) ? Qb : Kb;
#pragma unroll
            for (int j = 0; j < 8; j++) {
                int g = j * 256 + t;
                int row = g >> 5, seg = g & 31;
                *(bf16x8*)(o + (size_t)(m0 + row) * E_ + seg * 8) =
                    *(const bf16x8*)&ep[row * 264 + seg * 8];
            }
        }
        __syncthreads(); // ep reads done before next pass reuses stg/ep
    }

    gbar(&bars[0], 512);

    // ================= phase 2: flash (byte-identical R6 structure) ========
    {
        int lin = bid;
        int xcd = lin & 7, r8 = lin >> 3;
        int pair = (xcd << 1) | (r8 >> 5);
        int b = pair >> 2, slice = pair & 3, q0 = (r8 & 31) * 128;
        int key0 = slice * (S_ / NS_);
        const int nchunk = (S_ / NS_) / 32; // 32
        int wv = wid;

        bf16x8 qf[2][8];
#pragma unroll
        for (int u = 0; u < 2; u++) {
            const short* qrow = Qb + (size_t)(b * S_ + q0 + u * 64 + wv * 16 + idx) * E_ + quad * 8;
#pragma unroll
            for (int c = 0; c < 8; c++) qf[u][c] = *(const bf16x8*)(qrow + c * 32);
        }
        f32x4 oacc[2][16];
#pragma unroll
        for (int u = 0; u < 2; u++)
#pragma unroll
            for (int i = 0; i < 16; i++) oacc[u][i] = zf;
        float ls[2][4] = {{0, 0, 0, 0}, {0, 0, 0, 0}};

        const short* kg = Kb + (size_t)(b * S_ + key0) * E_ + lane * 8;
        const short* vg = Vtc + ((size_t)(b * 128 + (key0 >> 5))) * 8192 + lane * 8;
        short* psw = lds + 32768 + wv * 1280;
        unsigned int* pswu = (unsigned int*)psw;
        int vsw = (quad ^ ((idx >> 1) & 3)) << 3;

#pragma unroll
        for (int j = 0; j < 4; j++) gl_lds16(kg + (wv * 4 + j) * 512, &lds[(wv * 4 + j) * 512]);
#pragma unroll
        for (int j = 0; j < 4; j++) gl_lds16(vg + (wv * 4 + j) * 512, &lds[16384 + (wv * 4 + j) * 512]);
#pragma unroll
        for (int j = 0; j < 4; j++) gl_lds16(kg + 8192 + (wv * 4 + j) * 512, &lds[8192 + (wv * 4 + j) * 512]);
        __syncthreads();

        { // QK(0) + exp(0)
            f32x4 s[4] = {zf, zf, zf, zf};
            __builtin_amdgcn_s_setprio(1);
#pragma unroll
            for (int c = 0; c < 8; c++) {
                int p = (((c * 4 + quad) ^ (idx & 7)) << 3);
                bf16x8 k0 = *(const bf16x8*)&lds[idx * 256 + p];
                bf16x8 k1 = *(const bf16x8*)&lds[(16 + idx) * 256 + p];
                s[0] = __builtin_amdgcn_mfma_f32_16x16x32_bf16(qf[0][c], k0, s[0], 0, 0, 0);
                s[1] = __builtin_amdgcn_mfma_f32_16x16x32_bf16(qf[0][c], k1, s[1], 0, 0, 0);
                s[2] = __builtin_amdgcn_mfma_f32_16x16x32_bf16(qf[1][c], k0, s[2], 0, 0, 0);
                s[3] = __builtin_amdgcn_mfma_f32_16x16x32_bf16(qf[1][c], k1, s[3], 0, 0, 0);
            }
            __builtin_amdgcn_s_setprio(0);
#pragma unroll
            for (int u = 0; u < 2; u++)
#pragma unroll
                for (int r = 0; r < 4; r++) {
                    float p0 = __expf(s[u * 2][r]);
                    float p1 = __expf(s[u * 2 + 1][r]);
                    ls[u][r] += p0 + p1;
                    pswu[u * 320 + (quad * 4 + r) * 20 + idx] =
                        (unsigned int)bf16_rtne(p0) | ((unsigned int)bf16_rtne(p1) << 16);
                }
        }

        for (int ck = 0; ck < nchunk - 1; ck++) {
            __syncthreads();
            bf16x8 af0 = *(const bf16x8*)&psw[idx * 40 + quad * 8];
            bf16x8 af1 = *(const bf16x8*)&psw[640 + idx * 40 + quad * 8];
            if (ck + 2 < nchunk) {
                const short* ks = kg + (size_t)(ck + 2) * 8192;
                short* kd = lds + (ck & 1) * 8192;
#pragma unroll
                for (int j = 0; j < 4; j++) gl_lds16(ks + (wv * 4 + j) * 512, &kd[(wv * 4 + j) * 512]);
            }
            {
                const short* vs = vg + (size_t)(ck + 1) * 8192;
                short* vd = lds + 16384 + ((ck + 1) & 1) * 8192;
#pragma unroll
                for (int j = 0; j < 4; j++) gl_lds16(vs + (wv * 4 + j) * 512, &vd[(wv * 4 + j) * 512]);
            }
            const short* kc = lds + ((ck + 1) & 1) * 8192;
            f32x4 s[4] = {zf, zf, zf, zf};
            __builtin_amdgcn_s_setprio(1);
#pragma unroll
            for (int c = 0; c < 8; c++) {
                int p = (((c * 4 + quad) ^ (idx & 7)) << 3);
                bf16x8 k0 = *(const bf16x8*)&kc[idx * 256 + p];
                bf16x8 k1 = *(const bf16x8*)&kc[(16 + idx) * 256 + p];
                s[0] = __builtin_amdgcn_mfma_f32_16x16x32_bf16(qf[0][c], k0, s[0], 0, 0, 0);
                s[1] = __builtin_amdgcn_mfma_f32_16x16x32_bf16(qf[0][c], k1, s[1], 0, 0, 0);
                s[2] = __builtin_amdgcn_mfma_f32_16x16x32_bf16(qf[1][c], k0, s[2], 0, 0, 0);
                s[3] = __builtin_amdgcn_mfma_f32_16x16x32_bf16(qf[1][c], k1, s[3], 0, 0, 0);
            }
            __builtin_amdgcn_s_setprio(0);
#pragma unroll
            for (int u = 0; u < 2; u++)
#pragma unroll
                for (int r = 0; r < 4; r++) {
                    float p0 = __expf(s[u * 2][r]);
                    float p1 = __expf(s[u * 2 + 1][r]);
                    ls[u][r] += p0 + p1;
                    pswu[u * 320 + (quad * 4 + r) * 20 + idx] =
                        (unsigned int)bf16_rtne(p0) | ((unsigned int)bf16_rtne(p1) << 16);
                }
            const short* vc = lds + 16384 + (ck & 1) * 8192;
            __builtin_amdgcn_s_setprio(1);
#pragma unroll
            for (int ct = 0; ct < 16; ct++) {
                bf16x8 v = *(const bf16x8*)&vc[(ct * 16 + idx) * 32 + vsw];
                oacc[0][ct] = __builtin_amdgcn_mfma_f32_16x16x32_bf16(af0, v, oacc[0][ct], 0, 0, 0);
                oacc[1][ct] = __builtin_amdgcn_mfma_f32_16x16x32_bf16(af1, v, oacc[1][ct], 0, 0, 0);
            }
            __builtin_amdgcn_s_setprio(0);
        }
        __syncthreads();
        {
            bf16x8 af0 = *(const bf16x8*)&psw[idx * 40 + quad * 8];
            bf16x8 af1 = *(const bf16x8*)&psw[640 + idx * 40 + quad * 8];
            const short* vc = lds + 16384 + ((nchunk - 1) & 1) * 8192;
            __builtin_amdgcn_s_setprio(1);
#pragma unroll
            for (int ct = 0; ct < 16; ct++) {
                bf16x8 v = *(const bf16x8*)&vc[(ct * 16 + idx) * 32 + vsw];
                oacc[0][ct] = __builtin_amdgcn_mfma_f32_16x16x32_bf16(af0, v, oacc[0][ct], 0, 0, 0);
                oacc[1][ct] = __builtin_amdgcn_mfma_f32_16x16x32_bf16(af1, v, oacc[1][ct], 0, 0, 0);
            }
            __builtin_amdgcn_s_setprio(0);
        }
        __syncthreads(); // reuse kb/vb as epilogue scratch

#pragma unroll
        for (int u = 0; u < 2; u++)
#pragma unroll
            for (int r = 0; r < 4; r++) {
                float v = ls[u][r];
                v += __shfl_xor(v, 1);
                v += __shfl_xor(v, 2);
                v += __shfl_xor(v, 4);
                v += __shfl_xor(v, 8);
                if (idx == 0)
                    lpart[(size_t)slice * BS_ + b * S_ + q0 + u * 64 + wv * 16 + quad * 4 + r] = v;
            }

        short* scr = lds + wv * 8192;
#pragma unroll
        for (int u = 0; u < 2; u++)
#pragma unroll
            for (int ct = 0; ct < 16; ct++) {
                int e = ct * 16 + idx;
#pragma unroll
                for (int r = 0; r < 4; r++) {
                    int lr = quad * 4 + r;
                    scr[u * 4096 + lr * 256 + ((((e >> 3) ^ (lr & 7)) << 3) | (e & 7))] =
                        (short)bf16_rtne(oacc[u][ct][r]);
                }
            }
        f32x4 pacc[2] = {zf, zf};
#pragma unroll
        for (int c = 0; c < 8; c++) {
            const float* ws = wo + idx * E_ + c * 32 + quad * 8;
            bf16x8 bw = pack8(*(const f32x4*)ws, *(const f32x4*)(ws + 4));
#pragma unroll
            for (int u = 0; u < 2; u++) {
                bf16x8 pa = *(const bf16x8*)&scr[u * 4096 + idx * 256 +
                                                 (((c * 4 + quad) ^ (idx & 7)) << 3)];
                pacc[u] = __builtin_amdgcn_mfma_f32_16x16x32_bf16(pa, bw, pacc[u], 0, 0, 0);
            }
        }
#pragma unroll
        for (int u = 0; u < 2; u++)
#pragma unroll
            for (int r = 0; r < 4; r++) {
                int m = q0 + u * 64 + wv * 16 + quad * 4 + r;
                atomicAdd(&partial[((size_t)b * S_ + m) * NC_ + idx], pacc[u][r]);
            }
    }

    gbar(&bars[1], 512);

    // ================= phase 3: norm (2 elems/thread) ======================
#pragma unroll
    for (int k = 0; k < 2; k++) {
        int e = bid * 512 + k * 256 + t;
        int m = e >> 4, o = e & 15;
        float ltot = 0.f;
#pragma unroll
        for (int ns = 0; ns < NS_; ns++) ltot += lpart[(size_t)ns * BS_ + m];
        out[e] = partial[e] * (0.0625f / ltot) + bo[o];
    }
}

extern "C" void kernel_launch(void* const* d_in, const int* in_sizes, int n_in,
                              void* d_out, int out_size, void* d_ws, size_t ws_size,
                              hipStream_t stream) {
    const float* x  = (const float*)d_in[0];
    const float* wq = (const float*)d_in[1];
    const float* bq = (const float*)d_in[2];
    const float* wk = (const float*)d_in[3];
    const float* bk = (const float*)d_in[4];
    const float* wv = (const float*)d_in[5];
    const float* bv = (const float*)d_in[6];
    const float* wo = (const float*)d_in[7];
    const float* bo = (const float*)d_in[8];
    float* out = (float*)d_out;

    const size_t NEL = (size_t)BS_ * E_; // 4,194,304
    short* Qb = (short*)d_ws;
    short* Kb = Qb + NEL;
    short* Vtc = Kb + NEL;
    float* partial = (float*)(Vtc + NEL);        // BS_*NC_ f32 = 1 MB
    float* lpart = partial + (size_t)BS_ * NC_;  // NS_*BS_ f32 = 256 KB
    unsigned* bars = (unsigned*)(lpart + (size_t)NS_ * BS_);

    hipMemsetAsync(bars, 0, 2 * sizeof(unsigned), stream);
    fused<<<dim3(512), 256, 0, stream>>>(x, wq, wk, wv, bq, bk, bv, wo, bo,
                                         Qb, Kb, Vtc, partial, lpart, bars, out);
}

// Round 9
// 172.092 us; speedup vs baseline: 2.4294x; 2.4294x over previous
//
#include <hip/hip_runtime.h>
#include <hip/hip_bf16.h>

// B=4, S=4096, E=256, NC=16, fp32 in/out. 3 launches.
// R8 post-mortem encoded: v_cvt_pk_bf16_f32 on gfx950 is NOT RTNE (truncates;
// absmax 1.2e-4 -> 7.2e-3). ALL packs use the manual integer RTNE (pack8 /
// bf16_rtne), bit-stable for 8 rounds. Keeping R8's one validated win:
// flash's projection epilogue reads PREPACKED wbo (R4 vs R6 A/B: -2.7us),
// packed as a side job by qkv blocks 0-1.
//  qkv_gemm: x fp32->reg->bf16 prologue; w issue-early/write-late into
//            XOR-swizzled LDS dbuf, one barrier/K-step; zeroes partial;
//            packs wo->wbo (blocks 0-1); XCD-aware decode (x L2 hits).
//  flash:    R4/R6 proven structure (u=2, 2 blocks/CU, K/V dbuf + padded ps,
//            one barrier/chunk, one-behind PV, hoisted af, setprio, XCD
//            decode -> K/V L2-resident, fused wo-projection + atomicAdd).
//  norm_out: out[m][o] = partial[m][o] * (1/16)/ltot[m] + bo[o].
// R5 lesson: u=4 (256+ regs) -> 1 wave/SIMD -> latency exposure (102us).
// R7 lesson: persistent fusion + device-scope grid barriers -> L2 wb/inv
// catastrophe on non-coherent-L2 MI355X (418us). Stay 3-launch, u=2.

#define S_ 4096
#define E_ 256
#define B_ 4
#define NC_ 16
#define BS_ (B_ * S_)
#define NS_ 4

typedef __attribute__((ext_vector_type(8))) short bf16x8;
typedef __attribute__((ext_vector_type(4))) float f32x4;

__device__ __forceinline__ unsigned short bf16_rtne(float f) {
    unsigned int u = __float_as_uint(f);
    return (unsigned short)((u + 0x7FFFu + ((u >> 16) & 1u)) >> 16);
}
__device__ __forceinline__ bf16x8 pack8(f32x4 a, f32x4 b) {
    bf16x8 r;
#pragma unroll
    for (int i = 0; i < 4; i++) r[i] = (short)bf16_rtne(a[i]);
#pragma unroll
    for (int i = 0; i < 4; i++) r[4 + i] = (short)bf16_rtne(b[i]);
    return r;
}
__device__ __forceinline__ void gl_lds16(const void* g, void* lds) {
    __builtin_amdgcn_global_load_lds(
        (const __attribute__((address_space(1))) unsigned int*)g,
        (__attribute__((address_space(3))) unsigned int*)lds, 16, 0, 0);
}
// XOR swizzle on 16B LDS units: involution (mask from bits >=3 flips bits 0-2).
__device__ __forceinline__ int swz_u(int q) { return q ^ ((q >> 3) & 7); }

// ---------------------------------------------------------------------------
// qkv_gemm. 1-D grid 768. 256 thr = 4 waves; wave: 16 rows x 256 cols.
// XCD decode: xcd = bid&7; same m0's 3 sels co-located per XCD (x L2 hits).
// A: fp32 x rows -> registers (RTNE pack). B: w fp32 -> regs (issue-early)
// -> pack8 -> ds_write (write-late) into swizzled dbuf; one barrier/K-step.
// Side jobs: zero partial; blocks 0-1 pack wo -> wbo for flash.
// ---------------------------------------------------------------------------
__global__ __launch_bounds__(256) void qkv_gemm(
    const float* __restrict__ x, const float* __restrict__ wq,
    const float* __restrict__ wk, const float* __restrict__ wv,
    const float* __restrict__ bq, const float* __restrict__ bk,
    const float* __restrict__ bv, const float* __restrict__ wo,
    short* __restrict__ Qb, short* __restrict__ Kb, short* __restrict__ Vtc,
    short* __restrict__ wbo, float* __restrict__ partial) {
    __shared__ __align__(16) short stg[2][8192]; // 2 x 16KB: wt 1024 units
    __shared__ __align__(16) short epi[16896];   // 64x264 (Q/K) or 2x8192 (V)

    int t = threadIdx.x;
    int lin = blockIdx.x;
    int xcd = lin & 7, r8 = lin >> 3;
    int sel = r8 >> 5;
    int m0 = (((xcd << 5) | (r8 & 31))) * 64;
    int lane = t & 63, wid = t >> 6, quad = lane >> 4, idx = lane & 15;

    const float* wsel = (sel == 0) ? wq : (sel == 1) ? wk : wv;
    const float* bias = (sel == 0) ? bq : (sel == 1) ? bk : bv;

    // w fp32 sources: physical LDS unit q holds logical unit swz_u(q)
    const float* wsrc[4];
#pragma unroll
    for (int i = 0; i < 4; i++) {
        int q = i * 256 + t, u = swz_u(q);
        wsrc[i] = wsel + (size_t)(u >> 2) * E_ + (u & 3) * 8;
    }

    // prologue: w step0 -> regs (flight covers the side jobs + x pack below)
    f32x4 wf[8];
#pragma unroll
    for (int i = 0; i < 4; i++) {
        wf[i * 2] = *(const f32x4*)(wsrc[i]);
        wf[i * 2 + 1] = *(const f32x4*)(wsrc[i] + 4);
    }

    // zero partial: 262144 f32 over 196608 threads (2 each, guarded)
    {
        int z = lin * 256 + t;
        partial[z] = 0.f;
        if (z < BS_ * NC_ - 196608) partial[z + 196608] = 0.f;
    }
    // blocks 0-1: pack wo (16x256 fp32) -> wbo bf16 for flash's epilogue
    if (lin < 2) {
        int uo = lin * 256 + t; // 512 units of 8
        const float* ws = wo + (size_t)uo * 8;
        *(bf16x8*)(wbo + (size_t)uo * 8) =
            pack8(*(const f32x4*)ws, *(const f32x4*)(ws + 4));
    }

    // x rows -> registers: row m0+wid*16+idx, cols quad*8 + it*32 .. +7
    const float* xrow = x + (size_t)(m0 + wid * 16 + idx) * E_ + quad * 8;
    bf16x8 af[8];
#pragma unroll
    for (int it = 0; it < 8; it++) {
        f32x4 a0 = *(const f32x4*)(xrow + it * 32);
        f32x4 a1 = *(const f32x4*)(xrow + it * 32 + 4);
        af[it] = pack8(a0, a1);
    }

    // write w step0 into buf 0
#pragma unroll
    for (int i = 0; i < 4; i++)
        *(bf16x8*)&stg[0][(i * 256 + t) * 8] = pack8(wf[i * 2], wf[i * 2 + 1]);

    f32x4 zf = {0.f, 0.f, 0.f, 0.f};
    f32x4 acc[16];
#pragma unroll
    for (int i = 0; i < 16; i++) acc[i] = zf;

    int fo = (idx * 4 + quad) ^ (idx >> 1); // swizzled fragment unit offset

    __syncthreads(); // buf 0 visible to all waves

#pragma unroll
    for (int it = 0; it < 8; it++) {
        // issue-early: w loads for step it+1 (hide under MFMA cluster)
        if (it < 7) {
            int kc = (it + 1) * 32;
#pragma unroll
            for (int i = 0; i < 4; i++) {
                wf[i * 2] = *(const f32x4*)(wsrc[i] + kc);
                wf[i * 2 + 1] = *(const f32x4*)(wsrc[i] + kc + 4);
            }
        }
        const short* cw = &stg[it & 1][fo * 8];
        __builtin_amdgcn_s_setprio(1);
#pragma unroll
        for (int ct = 0; ct < 16; ct++)
            acc[ct] = __builtin_amdgcn_mfma_f32_16x16x32_bf16(
                af[it], *(const bf16x8*)&cw[ct * 512], acc[ct], 0, 0, 0);
        __builtin_amdgcn_s_setprio(0);
        // write-late: pack + ds_write into the buffer all waves finished
        // reading before the PREVIOUS barrier (dbuf-safe).
        if (it < 7) {
            short* d = stg[(it + 1) & 1];
#pragma unroll
            for (int i = 0; i < 4; i++)
                *(bf16x8*)&d[(i * 256 + t) * 8] = pack8(wf[i * 2], wf[i * 2 + 1]);
        }
        __syncthreads();
    }

    int qr = quad * 4;
    if (sel == 2) {
        // V: chunk slab, position = key-interleave permutation + 16B swizzle
#pragma unroll
        for (int ct = 0; ct < 16; ct++) {
            int e = ct * 16 + idx;
            float bb = bias[e];
#pragma unroll
            for (int r = 0; r < 4; r++) {
                int mr = wid * 16 + qr + r; // 0..63
                int ckg = mr >> 5, sin = mr & 31;
                int sp = ((sin & 15) << 1) | (sin >> 4); // interleaved position
                int pos = (sp >> 3) ^ ((e >> 1) & 3);
                epi[ckg * 8192 + e * 32 + pos * 8 + (sp & 7)] =
                    (short)bf16_rtne(acc[ct][r] + bb);
            }
        }
        __syncthreads();
        size_t base = ((size_t)((m0 >> 12) * 128 + ((m0 & (S_ - 1)) >> 5))) * 8192;
#pragma unroll
        for (int j = 0; j < 8; j++) {
            int unit = j * 256 + t;
            *(bf16x8*)(Vtc + base + (size_t)unit * 8) = *(const bf16x8*)&epi[unit * 8];
        }
    } else {
        float alpha = (sel == 0) ? 0.0625f : 1.0f;
#pragma unroll
        for (int ct = 0; ct < 16; ct++) {
            int n = ct * 16 + idx;
            float bb = bias[n];
#pragma unroll
            for (int r = 0; r < 4; r++) {
                int row = wid * 16 + qr + r;
                int col = (sel == 1) ? ((((n >> 3) ^ (row & 7)) << 3) | (n & 7)) : n;
                epi[row * 264 + col] = (short)bf16_rtne((acc[ct][r] + bb) * alpha);
            }
        }
        __syncthreads();
        short* out = (sel == 0) ? Qb : Kb;
#pragma unroll
        for (int j = 0; j < 8; j++) {
            int g = j * 256 + t;
            int row = g >> 5, seg = g & 31;
            *(bf16x8*)(out + (size_t)(m0 + row) * E_ + seg * 8) =
                *(const bf16x8*)&epi[row * 264 + seg * 8];
        }
    }
}

// ---------------------------------------------------------------------------
// Flash + fused out-projection. Proven structure; wbo PREPACKED (R4 A/B).
// 1-D grid 512, XCD decode (K/V L2-resident). LDS 74 KB.
// ---------------------------------------------------------------------------
__global__ __launch_bounds__(256, 2) void flash_attn(
    const short* __restrict__ Qb, const short* __restrict__ Kb,
    const short* __restrict__ Vtc, const short* __restrict__ wbo,
    float* __restrict__ partial, float* __restrict__ lpart) {
    __shared__ __align__(16) short lds[37888]; // 75776 B
    // kb(par) = lds + par*8192 ; vb(par) = lds + 16384 + par*8192 ; ps at 32768

    int t = threadIdx.x;
    int lin = blockIdx.x;                       // 0..511
    int xcd = lin & 7, r8 = lin >> 3;           // r8 0..63
    int pair = (xcd << 1) | (r8 >> 5);          // 0..15
    int b = pair >> 2, slice = pair & 3, q0 = (r8 & 31) * 128;
    int key0 = slice * (S_ / NS_);
    const int nchunk = (S_ / NS_) / 32; // 32
    int lane = t & 63, wv = t >> 6, quad = lane >> 4, idx = lane & 15;

    bf16x8 qf[2][8];
#pragma unroll
    for (int u = 0; u < 2; u++) {
        const short* qrow = Qb + (size_t)(b * S_ + q0 + u * 64 + wv * 16 + idx) * E_ + quad * 8;
#pragma unroll
        for (int c = 0; c < 8; c++) qf[u][c] = *(const bf16x8*)(qrow + c * 32);
    }

    f32x4 zf = {0.f, 0.f, 0.f, 0.f};
    f32x4 oacc[2][16];
#pragma unroll
    for (int u = 0; u < 2; u++)
#pragma unroll
        for (int i = 0; i < 16; i++) oacc[u][i] = zf;
    float ls[2][4] = {{0, 0, 0, 0}, {0, 0, 0, 0}};

    const short* kg = Kb + (size_t)(b * S_ + key0) * E_ + lane * 8;
    const short* vg = Vtc + ((size_t)(b * 128 + (key0 >> 5))) * 8192 + lane * 8;
    short* psw = lds + 32768 + wv * 1280; // per-wave 1280 shorts (2u x 16r x 20dw)
    unsigned int* pswu = (unsigned int*)psw;
    int vsw = (quad ^ ((idx >> 1) & 3)) << 3;

    // prologue: stage K(0), V(0), K(1)
#pragma unroll
    for (int j = 0; j < 4; j++) gl_lds16(kg + (wv * 4 + j) * 512, &lds[(wv * 4 + j) * 512]);
#pragma unroll
    for (int j = 0; j < 4; j++) gl_lds16(vg + (wv * 4 + j) * 512, &lds[16384 + (wv * 4 + j) * 512]);
#pragma unroll
    for (int j = 0; j < 4; j++) gl_lds16(kg + 8192 + (wv * 4 + j) * 512, &lds[8192 + (wv * 4 + j) * 512]);
    __syncthreads();

    // QK(0) + exp(0)
    {
        f32x4 s[4] = {zf, zf, zf, zf};
        __builtin_amdgcn_s_setprio(1);
#pragma unroll
        for (int c = 0; c < 8; c++) {
            int p = (((c * 4 + quad) ^ (idx & 7)) << 3);
            bf16x8 k0 = *(const bf16x8*)&lds[idx * 256 + p];
            bf16x8 k1 = *(const bf16x8*)&lds[(16 + idx) * 256 + p];
            s[0] = __builtin_amdgcn_mfma_f32_16x16x32_bf16(qf[0][c], k0, s[0], 0, 0, 0);
            s[1] = __builtin_amdgcn_mfma_f32_16x16x32_bf16(qf[0][c], k1, s[1], 0, 0, 0);
            s[2] = __builtin_amdgcn_mfma_f32_16x16x32_bf16(qf[1][c], k0, s[2], 0, 0, 0);
            s[3] = __builtin_amdgcn_mfma_f32_16x16x32_bf16(qf[1][c], k1, s[3], 0, 0, 0);
        }
        __builtin_amdgcn_s_setprio(0);
#pragma unroll
        for (int u = 0; u < 2; u++)
#pragma unroll
            for (int r = 0; r < 4; r++) {
                float p0 = __expf(s[u * 2][r]);
                float p1 = __expf(s[u * 2 + 1][r]);
                ls[u][r] += p0 + p1;
                pswu[u * 320 + (quad * 4 + r) * 20 + idx] =
                    (unsigned int)bf16_rtne(p0) | ((unsigned int)bf16_rtne(p1) << 16);
            }
    }

    for (int ck = 0; ck < nchunk - 1; ck++) {
        __syncthreads(); // drains K(ck+1), V(ck) DMAs (staged one full chunk ago)
        // ---- af(ck) read hoisted: full chunk of ds flight before PV needs it.
        bf16x8 af0 = *(const bf16x8*)&psw[idx * 40 + quad * 8];
        bf16x8 af1 = *(const bf16x8*)&psw[640 + idx * 40 + quad * 8];
        if (ck + 2 < nchunk) {
            const short* ks = kg + (size_t)(ck + 2) * 8192;
            short* kd = lds + (ck & 1) * 8192;
#pragma unroll
            for (int j = 0; j < 4; j++) gl_lds16(ks + (wv * 4 + j) * 512, &kd[(wv * 4 + j) * 512]);
        }
        {
            const short* vs = vg + (size_t)(ck + 1) * 8192;
            short* vd = lds + 16384 + ((ck + 1) & 1) * 8192;
#pragma unroll
            for (int j = 0; j < 4; j++) gl_lds16(vs + (wv * 4 + j) * 512, &vd[(wv * 4 + j) * 512]);
        }
        // ---- QK(ck+1) ----
        const short* kc = lds + ((ck + 1) & 1) * 8192;
        f32x4 s[4] = {zf, zf, zf, zf};
        __builtin_amdgcn_s_setprio(1);
#pragma unroll
        for (int c = 0; c < 8; c++) {
            int p = (((c * 4 + quad) ^ (idx & 7)) << 3);
            bf16x8 k0 = *(const bf16x8*)&kc[idx * 256 + p];
            bf16x8 k1 = *(const bf16x8*)&kc[(16 + idx) * 256 + p];
            s[0] = __builtin_amdgcn_mfma_f32_16x16x32_bf16(qf[0][c], k0, s[0], 0, 0, 0);
            s[1] = __builtin_amdgcn_mfma_f32_16x16x32_bf16(qf[0][c], k1, s[1], 0, 0, 0);
            s[2] = __builtin_amdgcn_mfma_f32_16x16x32_bf16(qf[1][c], k0, s[2], 0, 0, 0);
            s[3] = __builtin_amdgcn_mfma_f32_16x16x32_bf16(qf[1][c], k1, s[3], 0, 0, 0);
        }
        __builtin_amdgcn_s_setprio(0);
        // ---- exp(ck+1) -> ps (independent of PV(ck); hides under it) ----
#pragma unroll
        for (int u = 0; u < 2; u++)
#pragma unroll
            for (int r = 0; r < 4; r++) {
                float p0 = __expf(s[u * 2][r]);
                float p1 = __expf(s[u * 2 + 1][r]);
                ls[u][r] += p0 + p1;
                pswu[u * 320 + (quad * 4 + r) * 20 + idx] =
                    (unsigned int)bf16_rtne(p0) | ((unsigned int)bf16_rtne(p1) << 16);
            }
        // ---- PV(ck) ----
        const short* vc = lds + 16384 + (ck & 1) * 8192;
        __builtin_amdgcn_s_setprio(1);
#pragma unroll
        for (int ct = 0; ct < 16; ct++) {
            bf16x8 v = *(const bf16x8*)&vc[(ct * 16 + idx) * 32 + vsw];
            oacc[0][ct] = __builtin_amdgcn_mfma_f32_16x16x32_bf16(af0, v, oacc[0][ct], 0, 0, 0);
            oacc[1][ct] = __builtin_amdgcn_mfma_f32_16x16x32_bf16(af1, v, oacc[1][ct], 0, 0, 0);
        }
        __builtin_amdgcn_s_setprio(0);
    }
    __syncthreads(); // drain V(nchunk-1)
    {
        bf16x8 af0 = *(const bf16x8*)&psw[idx * 40 + quad * 8];
        bf16x8 af1 = *(const bf16x8*)&psw[640 + idx * 40 + quad * 8];
        const short* vc = lds + 16384 + ((nchunk - 1) & 1) * 8192;
        __builtin_amdgcn_s_setprio(1);
#pragma unroll
        for (int ct = 0; ct < 16; ct++) {
            bf16x8 v = *(const bf16x8*)&vc[(ct * 16 + idx) * 32 + vsw];
            oacc[0][ct] = __builtin_amdgcn_mfma_f32_16x16x32_bf16(af0, v, oacc[0][ct], 0, 0, 0);
            oacc[1][ct] = __builtin_amdgcn_mfma_f32_16x16x32_bf16(af1, v, oacc[1][ct], 0, 0, 0);
        }
        __builtin_amdgcn_s_setprio(0);
    }
    __syncthreads(); // all compute reads of kb/vb done; reuse as epilogue scratch

    // ---- row sums ----
#pragma unroll
    for (int u = 0; u < 2; u++)
#pragma unroll
        for (int r = 0; r < 4; r++) {
            float v = ls[u][r];
            v += __shfl_xor(v, 1);
            v += __shfl_xor(v, 2);
            v += __shfl_xor(v, 4);
            v += __shfl_xor(v, 8);
            if (idx == 0)
                lpart[(size_t)slice * BS_ + b * S_ + q0 + u * 64 + wv * 16 + quad * 4 + r] = v;
        }

    // ---- O scatter: per-wave 16 KB scratch (overlays kb/vb), transposed+swz
    short* scr = lds + wv * 8192;
#pragma unroll
    for (int u = 0; u < 2; u++)
#pragma unroll
        for (int ct = 0; ct < 16; ct++) {
            int e = ct * 16 + idx;
#pragma unroll
            for (int r = 0; r < 4; r++) {
                int lr = quad * 4 + r;
                scr[u * 4096 + lr * 256 + ((((e >> 3) ^ (lr & 7)) << 3) | (e & 7))] =
                    (short)bf16_rtne(oacc[u][ct][r]);
            }
        }
    // (no barrier needed: scr is per-wave, DS in-order)

    // ---- fused out-projection: 32q x 256E (bf16) x woT -> 32q x 16o fp32 ----
    f32x4 pacc[2] = {zf, zf};
#pragma unroll
    for (int c = 0; c < 8; c++) {
        bf16x8 bw = *(const bf16x8*)(wbo + idx * E_ + c * 32 + quad * 8);
#pragma unroll
        for (int u = 0; u < 2; u++) {
            bf16x8 pa = *(const bf16x8*)&scr[u * 4096 + idx * 256 +
                                             (((c * 4 + quad) ^ (idx & 7)) << 3)];
            pacc[u] = __builtin_amdgcn_mfma_f32_16x16x32_bf16(pa, bw, pacc[u], 0, 0, 0);
        }
    }
#pragma unroll
    for (int u = 0; u < 2; u++)
#pragma unroll
        for (int r = 0; r < 4; r++) {
            int m = q0 + u * 64 + wv * 16 + quad * 4 + r;
            atomicAdd(&partial[((size_t)b * S_ + m) * NC_ + idx], pacc[u][r]);
        }
}

// ---------------------------------------------------------------------------
// norm_out: out[m][o] = partial[m][o] * (1/16)/ltot[m] + bo[o]. Grid 1024x256.
// ---------------------------------------------------------------------------
__global__ __launch_bounds__(256) void norm_out(
    const float* __restrict__ partial, const float* __restrict__ lpart,
    const float* __restrict__ bo, float* __restrict__ out) {
    int t = threadIdx.x;
    int m = blockIdx.x * 16 + (t >> 4), o = t & 15;
    float ltot = 0.f;
#pragma unroll
    for (int ns = 0; ns < NS_; ns++) ltot += lpart[(size_t)ns * BS_ + m];
    size_t i = (size_t)m * NC_ + o;
    out[i] = partial[i] * (0.0625f / ltot) + bo[o];
}

extern "C" void kernel_launch(void* const* d_in, const int* in_sizes, int n_in,
                              void* d_out, int out_size, void* d_ws, size_t ws_size,
                              hipStream_t stream) {
    const float* x  = (const float*)d_in[0];
    const float* wq = (const float*)d_in[1];
    const float* bq = (const float*)d_in[2];
    const float* wk = (const float*)d_in[3];
    const float* bk = (const float*)d_in[4];
    const float* wv = (const float*)d_in[5];
    const float* bv = (const float*)d_in[6];
    const float* wo = (const float*)d_in[7];
    const float* bo = (const float*)d_in[8];
    float* out = (float*)d_out;

    const size_t NEL = (size_t)BS_ * E_; // 4,194,304
    // ws (shorts): Qb | Kb | Vtc | wbo(NC*E) | partial f32 | lpart f32
    short* Qb = (short*)d_ws;
    short* Kb = Qb + NEL;
    short* Vtc = Kb + NEL;
    short* wbo = Vtc + NEL;
    float* partial = (float*)(wbo + (size_t)NC_ * E_);  // BS_*NC_ f32 = 1 MB
    float* lpart = partial + (size_t)BS_ * NC_;         // NS_*BS_ f32 = 256 KB

    qkv_gemm<<<dim3(768), 256, 0, stream>>>(x, wq, wk, wv, bq, bk, bv, wo,
                                            Qb, Kb, Vtc, wbo, partial);
    flash_attn<<<dim3(512), 256, 0, stream>>>(Qb, Kb, Vtc, wbo, partial, lpart);
    norm_out<<<dim3(BS_ / 16), 256, 0, stream>>>(partial, lpart, bo, out);
}

// Round 10
// 168.775 us; speedup vs baseline: 2.4772x; 1.0197x over previous
//
#include <hip/hip_runtime.h>
#include <hip/hip_bf16.h>

// B=4, S=4096, E=256, NC=16, fp32 in/out. 3 launches.
// R10: (1) qkv register-pressure rewrite — af[8] full preload (32 VGPR live
// across the whole unrolled loop) replaced by a 2-deep rolling x pipeline
// (xf issue-early with wf, pack write-late); __launch_bounds__(256,2) forces
// <=256 regs/wave (R5 lesson: the 256-reg cliff is real). Theory: qkv ~55-65us
// by subtraction (R7: fixed harness overhead ~23us) vs <=8us static model ->
// register bloat/spill is the last standing explanation.
// (2) flash epilogue scr row stride 256->264 shorts: O-scatter scalar writes
// were 4-way bank-conflicted; pad spreads quads (lr*4 term). scr overlays the
// dead ps region (4x9472=37888 exact); address-constants only, VGPR stays 128.
// R8 lesson: v_cvt_pk_bf16_f32 is NOT RTNE on gfx950 — all packs stay manual
// integer RTNE. R7 lesson: no device-scope fences/grid barriers. R5: u=2 only.

#define S_ 4096
#define E_ 256
#define B_ 4
#define NC_ 16
#define BS_ (B_ * S_)
#define NS_ 4

typedef __attribute__((ext_vector_type(8))) short bf16x8;
typedef __attribute__((ext_vector_type(4))) float f32x4;

__device__ __forceinline__ unsigned short bf16_rtne(float f) {
    unsigned int u = __float_as_uint(f);
    return (unsigned short)((u + 0x7FFFu + ((u >> 16) & 1u)) >> 16);
}
__device__ __forceinline__ bf16x8 pack8(f32x4 a, f32x4 b) {
    bf16x8 r;
#pragma unroll
    for (int i = 0; i < 4; i++) r[i] = (short)bf16_rtne(a[i]);
#pragma unroll
    for (int i = 0; i < 4; i++) r[4 + i] = (short)bf16_rtne(b[i]);
    return r;
}
__device__ __forceinline__ void gl_lds16(const void* g, void* lds) {
    __builtin_amdgcn_global_load_lds(
        (const __attribute__((address_space(1))) unsigned int*)g,
        (__attribute__((address_space(3))) unsigned int*)lds, 16, 0, 0);
}
// XOR swizzle on 16B LDS units: involution (mask from bits >=3 flips bits 0-2).
__device__ __forceinline__ int swz_u(int q) { return q ^ ((q >> 3) & 7); }

// ---------------------------------------------------------------------------
// qkv_gemm. 1-D grid 768. 256 thr = 4 waves; wave: 16 rows x 256 cols.
// XCD decode: xcd = bid&7; same m0's 3 sels co-located per XCD (x L2 hits).
// A: x fp32 -> regs in a 2-deep rolling pipeline (xf issued with wf, packed
// write-late) — af_cur only 4 regs live vs 32 for the old full preload.
// B: w fp32 -> regs (issue-early) -> pack8 -> ds_write (write-late) into
// swizzled dbuf; one barrier/K-step. launch_bounds(256,2): cap 256 regs/wave.
// Side jobs: zero partial; blocks 0-1 pack wo -> wbo for flash.
// ---------------------------------------------------------------------------
__global__ __launch_bounds__(256, 2) void qkv_gemm(
    const float* __restrict__ x, const float* __restrict__ wq,
    const float* __restrict__ wk, const float* __restrict__ wv,
    const float* __restrict__ bq, const float* __restrict__ bk,
    const float* __restrict__ bv, const float* __restrict__ wo,
    short* __restrict__ Qb, short* __restrict__ Kb, short* __restrict__ Vtc,
    short* __restrict__ wbo, float* __restrict__ partial) {
    __shared__ __align__(16) short stg[2][8192]; // 2 x 16KB: wt 1024 units
    __shared__ __align__(16) short epi[16896];   // 64x264 (Q/K) or 2x8192 (V)

    int t = threadIdx.x;
    int lin = blockIdx.x;
    int xcd = lin & 7, r8 = lin >> 3;
    int sel = r8 >> 5;
    int m0 = (((xcd << 5) | (r8 & 31))) * 64;
    int lane = t & 63, wid = t >> 6, quad = lane >> 4, idx = lane & 15;

    const float* wsel = (sel == 0) ? wq : (sel == 1) ? wk : wv;
    const float* bias = (sel == 0) ? bq : (sel == 1) ? bk : bv;

    // w fp32 sources: physical LDS unit q holds logical unit swz_u(q)
    const float* wsrc[4];
#pragma unroll
    for (int i = 0; i < 4; i++) {
        int q = i * 256 + t, u = swz_u(q);
        wsrc[i] = wsel + (size_t)(u >> 2) * E_ + (u & 3) * 8;
    }

    // prologue: w step0 + x step0 -> regs (flight covers the side jobs)
    f32x4 wf[8];
#pragma unroll
    for (int i = 0; i < 4; i++) {
        wf[i * 2] = *(const f32x4*)(wsrc[i]);
        wf[i * 2 + 1] = *(const f32x4*)(wsrc[i] + 4);
    }
    const float* xrow = x + (size_t)(m0 + wid * 16 + idx) * E_ + quad * 8;
    f32x4 xa = *(const f32x4*)(xrow);
    f32x4 xb = *(const f32x4*)(xrow + 4);

    // zero partial: 262144 f32 over 196608 threads (2 each, guarded)
    {
        int z = lin * 256 + t;
        partial[z] = 0.f;
        if (z < BS_ * NC_ - 196608) partial[z + 196608] = 0.f;
    }
    // blocks 0-1: pack wo (16x256 fp32) -> wbo bf16 for flash's epilogue
    if (lin < 2) {
        int uo = lin * 256 + t; // 512 units of 8
        const float* ws = wo + (size_t)uo * 8;
        *(bf16x8*)(wbo + (size_t)uo * 8) =
            pack8(*(const f32x4*)ws, *(const f32x4*)(ws + 4));
    }

    // pack step0 A-fragment; write w step0 into buf 0
    bf16x8 afc = pack8(xa, xb);
#pragma unroll
    for (int i = 0; i < 4; i++)
        *(bf16x8*)&stg[0][(i * 256 + t) * 8] = pack8(wf[i * 2], wf[i * 2 + 1]);

    f32x4 zf = {0.f, 0.f, 0.f, 0.f};
    f32x4 acc[16];
#pragma unroll
    for (int i = 0; i < 16; i++) acc[i] = zf;

    int fo = (idx * 4 + quad) ^ (idx >> 1); // swizzled fragment unit offset

    __syncthreads(); // buf 0 visible to all waves

#pragma unroll
    for (int it = 0; it < 8; it++) {
        // issue-early: w + x loads for step it+1 (hide under MFMA cluster)
        if (it < 7) {
            int kc = (it + 1) * 32;
#pragma unroll
            for (int i = 0; i < 4; i++) {
                wf[i * 2] = *(const f32x4*)(wsrc[i] + kc);
                wf[i * 2 + 1] = *(const f32x4*)(wsrc[i] + kc + 4);
            }
            xa = *(const f32x4*)(xrow + kc);
            xb = *(const f32x4*)(xrow + kc + 4);
        }
        const short* cw = &stg[it & 1][fo * 8];
        __builtin_amdgcn_s_setprio(1);
#pragma unroll
        for (int ct = 0; ct < 16; ct++)
            acc[ct] = __builtin_amdgcn_mfma_f32_16x16x32_bf16(
                afc, *(const bf16x8*)&cw[ct * 512], acc[ct], 0, 0, 0);
        __builtin_amdgcn_s_setprio(0);
        // write-late: pack + ds_write into the buffer all waves finished
        // reading before the PREVIOUS barrier (dbuf-safe); roll af.
        if (it < 7) {
            short* d = stg[(it + 1) & 1];
#pragma unroll
            for (int i = 0; i < 4; i++)
                *(bf16x8*)&d[(i * 256 + t) * 8] = pack8(wf[i * 2], wf[i * 2 + 1]);
            afc = pack8(xa, xb);
        }
        __syncthreads();
    }

    int qr = quad * 4;
    if (sel == 2) {
        // V: chunk slab, position = key-interleave permutation + 16B swizzle
#pragma unroll
        for (int ct = 0; ct < 16; ct++) {
            int e = ct * 16 + idx;
            float bb = bias[e];
#pragma unroll
            for (int r = 0; r < 4; r++) {
                int mr = wid * 16 + qr + r; // 0..63
                int ckg = mr >> 5, sin = mr & 31;
                int sp = ((sin & 15) << 1) | (sin >> 4); // interleaved position
                int pos = (sp >> 3) ^ ((e >> 1) & 3);
                epi[ckg * 8192 + e * 32 + pos * 8 + (sp & 7)] =
                    (short)bf16_rtne(acc[ct][r] + bb);
            }
        }
        __syncthreads();
        size_t base = ((size_t)((m0 >> 12) * 128 + ((m0 & (S_ - 1)) >> 5))) * 8192;
#pragma unroll
        for (int j = 0; j < 8; j++) {
            int unit = j * 256 + t;
            *(bf16x8*)(Vtc + base + (size_t)unit * 8) = *(const bf16x8*)&epi[unit * 8];
        }
    } else {
        float alpha = (sel == 0) ? 0.0625f : 1.0f;
#pragma unroll
        for (int ct = 0; ct < 16; ct++) {
            int n = ct * 16 + idx;
            float bb = bias[n];
#pragma unroll
            for (int r = 0; r < 4; r++) {
                int row = wid * 16 + qr + r;
                int col = (sel == 1) ? ((((n >> 3) ^ (row & 7)) << 3) | (n & 7)) : n;
                epi[row * 264 + col] = (short)bf16_rtne((acc[ct][r] + bb) * alpha);
            }
        }
        __syncthreads();
        short* out = (sel == 0) ? Qb : Kb;
#pragma unroll
        for (int j = 0; j < 8; j++) {
            int g = j * 256 + t;
            int row = g >> 5, seg = g & 31;
            *(bf16x8*)(out + (size_t)(m0 + row) * E_ + seg * 8) =
                *(const bf16x8*)&epi[row * 264 + seg * 8];
        }
    }
}

// ---------------------------------------------------------------------------
// Flash + fused out-projection. Proven structure; wbo PREPACKED (R4 A/B).
// Epilogue scr stride 264 (anti-4-way padding; overlays kb/vb + dead ps).
// 1-D grid 512, XCD decode (K/V L2-resident). LDS 74 KB.
// ---------------------------------------------------------------------------
__global__ __launch_bounds__(256, 2) void flash_attn(
    const short* __restrict__ Qb, const short* __restrict__ Kb,
    const short* __restrict__ Vtc, const short* __restrict__ wbo,
    float* __restrict__ partial, float* __restrict__ lpart) {
    __shared__ __align__(16) short lds[37888]; // 75776 B
    // kb(par) = lds + par*8192 ; vb(par) = lds + 16384 + par*8192 ; ps at 32768

    int t = threadIdx.x;
    int lin = blockIdx.x;                       // 0..511
    int xcd = lin & 7, r8 = lin >> 3;           // r8 0..63
    int pair = (xcd << 1) | (r8 >> 5);          // 0..15
    int b = pair >> 2, slice = pair & 3, q0 = (r8 & 31) * 128;
    int key0 = slice * (S_ / NS_);
    const int nchunk = (S_ / NS_) / 32; // 32
    int lane = t & 63, wv = t >> 6, quad = lane >> 4, idx = lane & 15;

    bf16x8 qf[2][8];
#pragma unroll
    for (int u = 0; u < 2; u++) {
        const short* qrow = Qb + (size_t)(b * S_ + q0 + u * 64 + wv * 16 + idx) * E_ + quad * 8;
#pragma unroll
        for (int c = 0; c < 8; c++) qf[u][c] = *(const bf16x8*)(qrow + c * 32);
    }

    f32x4 zf = {0.f, 0.f, 0.f, 0.f};
    f32x4 oacc[2][16];
#pragma unroll
    for (int u = 0; u < 2; u++)
#pragma unroll
        for (int i = 0; i < 16; i++) oacc[u][i] = zf;
    float ls[2][4] = {{0, 0, 0, 0}, {0, 0, 0, 0}};

    const short* kg = Kb + (size_t)(b * S_ + key0) * E_ + lane * 8;
    const short* vg = Vtc + ((size_t)(b * 128 + (key0 >> 5))) * 8192 + lane * 8;
    short* psw = lds + 32768 + wv * 1280; // per-wave 1280 shorts (2u x 16r x 20dw)
    unsigned int* pswu = (unsigned int*)psw;
    int vsw = (quad ^ ((idx >> 1) & 3)) << 3;

    // prologue: stage K(0), V(0), K(1)
#pragma unroll
    for (int j = 0; j < 4; j++) gl_lds16(kg + (wv * 4 + j) * 512, &lds[(wv * 4 + j) * 512]);
#pragma unroll
    for (int j = 0; j < 4; j++) gl_lds16(vg + (wv * 4 + j) * 512, &lds[16384 + (wv * 4 + j) * 512]);
#pragma unroll
    for (int j = 0; j < 4; j++) gl_lds16(kg + 8192 + (wv * 4 + j) * 512, &lds[8192 + (wv * 4 + j) * 512]);
    __syncthreads();

    // QK(0) + exp(0)
    {
        f32x4 s[4] = {zf, zf, zf, zf};
        __builtin_amdgcn_s_setprio(1);
#pragma unroll
        for (int c = 0; c < 8; c++) {
            int p = (((c * 4 + quad) ^ (idx & 7)) << 3);
            bf16x8 k0 = *(const bf16x8*)&lds[idx * 256 + p];
            bf16x8 k1 = *(const bf16x8*)&lds[(16 + idx) * 256 + p];
            s[0] = __builtin_amdgcn_mfma_f32_16x16x32_bf16(qf[0][c], k0, s[0], 0, 0, 0);
            s[1] = __builtin_amdgcn_mfma_f32_16x16x32_bf16(qf[0][c], k1, s[1], 0, 0, 0);
            s[2] = __builtin_amdgcn_mfma_f32_16x16x32_bf16(qf[1][c], k0, s[2], 0, 0, 0);
            s[3] = __builtin_amdgcn_mfma_f32_16x16x32_bf16(qf[1][c], k1, s[3], 0, 0, 0);
        }
        __builtin_amdgcn_s_setprio(0);
#pragma unroll
        for (int u = 0; u < 2; u++)
#pragma unroll
            for (int r = 0; r < 4; r++) {
                float p0 = __expf(s[u * 2][r]);
                float p1 = __expf(s[u * 2 + 1][r]);
                ls[u][r] += p0 + p1;
                pswu[u * 320 + (quad * 4 + r) * 20 + idx] =
                    (unsigned int)bf16_rtne(p0) | ((unsigned int)bf16_rtne(p1) << 16);
            }
    }

    for (int ck = 0; ck < nchunk - 1; ck++) {
        __syncthreads(); // drains K(ck+1), V(ck) DMAs (staged one full chunk ago)
        // ---- af(ck) read hoisted: full chunk of ds flight before PV needs it.
        bf16x8 af0 = *(const bf16x8*)&psw[idx * 40 + quad * 8];
        bf16x8 af1 = *(const bf16x8*)&psw[640 + idx * 40 + quad * 8];
        if (ck + 2 < nchunk) {
            const short* ks = kg + (size_t)(ck + 2) * 8192;
            short* kd = lds + (ck & 1) * 8192;
#pragma unroll
            for (int j = 0; j < 4; j++) gl_lds16(ks + (wv * 4 + j) * 512, &kd[(wv * 4 + j) * 512]);
        }
        {
            const short* vs = vg + (size_t)(ck + 1) * 8192;
            short* vd = lds + 16384 + ((ck + 1) & 1) * 8192;
#pragma unroll
            for (int j = 0; j < 4; j++) gl_lds16(vs + (wv * 4 + j) * 512, &vd[(wv * 4 + j) * 512]);
        }
        // ---- QK(ck+1) ----
        const short* kc = lds + ((ck + 1) & 1) * 8192;
        f32x4 s[4] = {zf, zf, zf, zf};
        __builtin_amdgcn_s_setprio(1);
#pragma unroll
        for (int c = 0; c < 8; c++) {
            int p = (((c * 4 + quad) ^ (idx & 7)) << 3);
            bf16x8 k0 = *(const bf16x8*)&kc[idx * 256 + p];
            bf16x8 k1 = *(const bf16x8*)&kc[(16 + idx) * 256 + p];
            s[0] = __builtin_amdgcn_mfma_f32_16x16x32_bf16(qf[0][c], k0, s[0], 0, 0, 0);
            s[1] = __builtin_amdgcn_mfma_f32_16x16x32_bf16(qf[0][c], k1, s[1], 0, 0, 0);
            s[2] = __builtin_amdgcn_mfma_f32_16x16x32_bf16(qf[1][c], k0, s[2], 0, 0, 0);
            s[3] = __builtin_amdgcn_mfma_f32_16x16x32_bf16(qf[1][c], k1, s[3], 0, 0, 0);
        }
        __builtin_amdgcn_s_setprio(0);
        // ---- exp(ck+1) -> ps (independent of PV(ck); hides under it) ----
#pragma unroll
        for (int u = 0; u < 2; u++)
#pragma unroll
            for (int r = 0; r < 4; r++) {
                float p0 = __expf(s[u * 2][r]);
                float p1 = __expf(s[u * 2 + 1][r]);
                ls[u][r] += p0 + p1;
                pswu[u * 320 + (quad * 4 + r) * 20 + idx] =
                    (unsigned int)bf16_rtne(p0) | ((unsigned int)bf16_rtne(p1) << 16);
            }
        // ---- PV(ck) ----
        const short* vc = lds + 16384 + (ck & 1) * 8192;
        __builtin_amdgcn_s_setprio(1);
#pragma unroll
        for (int ct = 0; ct < 16; ct++) {
            bf16x8 v = *(const bf16x8*)&vc[(ct * 16 + idx) * 32 + vsw];
            oacc[0][ct] = __builtin_amdgcn_mfma_f32_16x16x32_bf16(af0, v, oacc[0][ct], 0, 0, 0);
            oacc[1][ct] = __builtin_amdgcn_mfma_f32_16x16x32_bf16(af1, v, oacc[1][ct], 0, 0, 0);
        }
        __builtin_amdgcn_s_setprio(0);
    }
    __syncthreads(); // drain V(nchunk-1)
    {
        bf16x8 af0 = *(const bf16x8*)&psw[idx * 40 + quad * 8];
        bf16x8 af1 = *(const bf16x8*)&psw[640 + idx * 40 + quad * 8];
        const short* vc = lds + 16384 + ((nchunk - 1) & 1) * 8192;
        __builtin_amdgcn_s_setprio(1);
#pragma unroll
        for (int ct = 0; ct < 16; ct++) {
            bf16x8 v = *(const bf16x8*)&vc[(ct * 16 + idx) * 32 + vsw];
            oacc[0][ct] = __builtin_amdgcn_mfma_f32_16x16x32_bf16(af0, v, oacc[0][ct], 0, 0, 0);
            oacc[1][ct] = __builtin_amdgcn_mfma_f32_16x16x32_bf16(af1, v, oacc[1][ct], 0, 0, 0);
        }
        __builtin_amdgcn_s_setprio(0);
    }
    __syncthreads(); // all compute reads of kb/vb/ps done; reuse ALL as scratch

    // ---- row sums ----
#pragma unroll
    for (int u = 0; u < 2; u++)
#pragma unroll
        for (int r = 0; r < 4; r++) {
            float v = ls[u][r];
            v += __shfl_xor(v, 1);
            v += __shfl_xor(v, 2);
            v += __shfl_xor(v, 4);
            v += __shfl_xor(v, 8);
            if (idx == 0)
                lpart[(size_t)slice * BS_ + b * S_ + q0 + u * 64 + wv * 16 + quad * 4 + r] = v;
        }

    // ---- O scatter: per-wave 18.5 KB scratch, row stride 264 (padded so the
    // scalar b16 writes spread quads across banks; reads keep the col swizzle).
    short* scr = lds + wv * 9472; // 4 x 9472 = 37888 (exact fit incl. dead ps)
#pragma unroll
    for (int u = 0; u < 2; u++)
#pragma unroll
        for (int ct = 0; ct < 16; ct++) {
            int e = ct * 16 + idx;
#pragma unroll
            for (int r = 0; r < 4; r++) {
                int lr = quad * 4 + r;
                scr[u * 4224 + lr * 264 + ((((e >> 3) ^ (lr & 7)) << 3) | (e & 7))] =
                    (short)bf16_rtne(oacc[u][ct][r]);
            }
        }
    // (no barrier needed: scr is per-wave, DS in-order)

    // ---- fused out-projection: 32q x 256E (bf16) x woT -> 32q x 16o fp32 ----
    f32x4 pacc[2] = {zf, zf};
#pragma unroll
    for (int c = 0; c < 8; c++) {
        bf16x8 bw = *(const bf16x8*)(wbo + idx * E_ + c * 32 + quad * 8);
#pragma unroll
        for (int u = 0; u < 2; u++) {
            bf16x8 pa = *(const bf16x8*)&scr[u * 4224 + idx * 264 +
                                             (((c * 4 + quad) ^ (idx & 7)) << 3)];
            pacc[u] = __builtin_amdgcn_mfma_f32_16x16x32_bf16(pa, bw, pacc[u], 0, 0, 0);
        }
    }
#pragma unroll
    for (int u = 0; u < 2; u++)
#pragma unroll
        for (int r = 0; r < 4; r++) {
            int m = q0 + u * 64 + wv * 16 + quad * 4 + r;
            atomicAdd(&partial[((size_t)b * S_ + m) * NC_ + idx], pacc[u][r]);
        }
}

// ---------------------------------------------------------------------------
// norm_out: out[m][o] = partial[m][o] * (1/16)/ltot[m] + bo[o]. Grid 1024x256.
// ---------------------------------------------------------------------------
__global__ __launch_bounds__(256) void norm_out(
    const float* __restrict__ partial, const float* __restrict__ lpart,
    const float* __restrict__ bo, float* __restrict__ out) {
    int t = threadIdx.x;
    int m = blockIdx.x * 16 + (t >> 4), o = t & 15;
    float ltot = 0.f;
#pragma unroll
    for (int ns = 0; ns < NS_; ns++) ltot += lpart[(size_t)ns * BS_ + m];
    size_t i = (size_t)m * NC_ + o;
    out[i] = partial[i] * (0.0625f / ltot) + bo[o];
}

extern "C" void kernel_launch(void* const* d_in, const int* in_sizes, int n_in,
                              void* d_out, int out_size, void* d_ws, size_t ws_size,
                              hipStream_t stream) {
    const float* x  = (const float*)d_in[0];
    const float* wq = (const float*)d_in[1];
    const float* bq = (const float*)d_in[2];
    const float* wk = (const float*)d_in[3];
    const float* bk = (const float*)d_in[4];
    const float* wv = (const float*)d_in[5];
    const float* bv = (const float*)d_in[6];
    const float* wo = (const float*)d_in[7];
    const float* bo = (const float*)d_in[8];
    float* out = (float*)d_out;

    const size_t NEL = (size_t)BS_ * E_; // 4,194,304
    // ws (shorts): Qb | Kb | Vtc | wbo(NC*E) | partial f32 | lpart f32
    short* Qb = (short*)d_ws;
    short* Kb = Qb + NEL;
    short* Vtc = Kb + NEL;
    short* wbo = Vtc + NEL;
    float* partial = (float*)(wbo + (size_t)NC_ * E_);  // BS_*NC_ f32 = 1 MB
    float* lpart = partial + (size_t)BS_ * NC_;         // NS_*BS_ f32 = 256 KB

    qkv_gemm<<<dim3(768), 256, 0, stream>>>(x, wq, wk, wv, bq, bk, bv, wo,
                                            Qb, Kb, Vtc, wbo, partial);
    flash_attn<<<dim3(512), 256, 0, stream>>>(Qb, Kb, Vtc, wbo, partial, lpart);
    norm_out<<<dim3(BS_ / 16), 256, 0, stream>>>(partial, lpart, bo, out);
}